// Round 7
// baseline (155.852 us; speedup 1.0000x reference)
//
#include <hip/hip_runtime.h>

// ---------------------------------------------------------------------------
// Problem constants
// ---------------------------------------------------------------------------
#define BATCH   16384
#define NF      16
#define OUTD    256
#define MTOT    4844
#define NK      5120        // permuted+padded K (80 chunks of 64)
#define NCHUNK  80
#define NIV     20          // intervals of 4 chunks
#define TROW    155         // T row stride (words): odd -> conflict-free column reads
#define NCREAL  5080        // real+group-padded columns

// ---------------------------------------------------------------------------
// Compile-time plan: permuted K-axis of (L, R-run) groups
//   T row layout: for c=0..15: [x_c, d2[c][c..15]]; [152]=1, [153]=[154]=0
//   group (a<=b): L = pos(d2[a][b]), R over [pos_x(b), 152)  (deg3+deg4)
//   unit group:   L = 152,           R over [0,152)          (deg1+deg2)
// ---------------------------------------------------------------------------
struct Plan {
    unsigned cplan[NCHUNK * 16];  // per quad: L | R0<<16 (pad: 153|152<<16)
    short    perm[NK];            // original column index or -1 (W=0)
    unsigned d2t[136];            // srcA | srcB<<10 | dst<<20 (word offsets)
    int ncols; int nreal; bool ok;
};

constexpr Plan make_plan() {
    Plan P{};
    int posx[17] = {};
    for (int c = 0; c <= 16; ++c) posx[c] = 17 * c - c * (c - 1) / 2;
    int S1t[16], Id2t[16], b3[16], b4[16];
    for (int j = 0; j < 16; ++j) { S1t[j] = 16 * j - j * (j - 1) / 2; Id2t[j] = 16 + S1t[j]; }
    { int s = 152; for (int j = 0; j < 16; ++j) { b3[j] = s; s += 152 - Id2t[j]; } }
    { int s = 968; for (int j = 0; j < 16; ++j) { b4[j] = s; s += 968 - b3[j]; } }
    { int idx = 0;
      for (int c = 0; c < 16; ++c)
        for (int d = c; d < 16; ++d)
            P.d2t[idx++] = (unsigned)posx[c] | ((unsigned)posx[d] << 10)
                         | ((unsigned)(posx[c] + 1 + (d - c)) << 20);
    }
    for (int q = 0; q < NCHUNK * 16; ++q) P.cplan[q] = 153u | (152u << 16);
    for (int k = 0; k < NK; ++k) P.perm[k] = -1;

    int k = 0;
    for (int p = 0; p < 152; ++p) {                       // unit group
        if ((k & 3) == 0) P.cplan[k >> 2] = 152u | ((unsigned)p << 16);
        int c = 0; while (posx[c + 1] <= p) ++c;
        int m;
        if (p == posx[c]) m = c;                          // deg1
        else { int d = c + (p - posx[c] - 1); m = 16 + S1t[c] + (d - c); }  // deg2
        P.perm[k++] = (short)m;
    }
    for (int b = 0; b < 16; ++b)
      for (int a = 0; a <= b; ++a) {                      // group (a,b)
        const int L = posx[a] + 1 + (b - a);
        const int st = posx[b], len = 152 - st, plen = (len + 3) & ~3;
        for (int off = 0; off < plen; ++off) {
            if ((k & 3) == 0) P.cplan[k >> 2] = (unsigned)L | ((unsigned)(st + off) << 16);
            if (off < len) {
                const int p = st + off;
                int c = 0; while (posx[c + 1] <= p) ++c;
                int m;
                if (p == posx[c]) {                        // deg3 {a,b,c}
                    m = b3[a] + (16 + S1t[b] + (c - b)) - Id2t[a];
                } else {                                   // deg4 {a,b,c,d}
                    const int d = c + (p - posx[c] - 1);
                    const int o3 = b3[b] + (16 + S1t[c] + (d - c)) - Id2t[b];
                    m = b4[a] + o3 - b3[a];
                }
                P.perm[k] = (short)m;
            }
            ++k;
        }
      }
    P.ncols = k;
    unsigned bm[152] = {};
    int cnt = 0; bool ok = (k == NCREAL);
    for (int kk = 0; kk < NK; ++kk) {
        const int m = P.perm[kk];
        if (m >= 0) {
            if (m >= MTOT || (bm[m >> 5] & (1u << (m & 31)))) { ok = false; break; }
            bm[m >> 5] |= 1u << (m & 31); ++cnt;
        }
    }
    if (cnt != MTOT) ok = false;
    P.nreal = cnt; P.ok = ok;
    return P;
}
constexpr Plan h_plan = make_plan();
static_assert(h_plan.ncols == NCREAL, "padded col count");
static_assert(h_plan.ok, "perm bijection onto [0,4844)");
__device__ const Plan g_plan = make_plan();

// ---------------------------------------------------------------------------
typedef __attribute__((ext_vector_type(8))) short    bf16x8;
typedef __attribute__((ext_vector_type(4))) float    f32x4;
typedef __attribute__((ext_vector_type(4))) unsigned uint4v;
typedef __attribute__((ext_vector_type(2))) unsigned u32x2;

__device__ inline unsigned bfpack2(float lo, float hi) {
    unsigned ul = __float_as_uint(lo), uh = __float_as_uint(hi);
    ul = (ul + 0x7fffu + ((ul >> 16) & 1u)) >> 16;
    uh = (uh + 0x7fffu + ((uh >> 16) & 1u)) & 0xffff0000u;
    return ul | uh;
}

// ---------------------------------------------------------------------------
// W fp32 [256][4844] -> bf16 [256][NK], column-permuted, pads zero-filled
// ---------------------------------------------------------------------------
__global__ __launch_bounds__(256) void wconv_kernel(
    const float* __restrict__ W, unsigned* __restrict__ Wb)
{
    const int r = blockIdx.x;
    const float* Wr = W + (size_t)r * MTOT;
    for (int i = threadIdx.x; i < NK / 2; i += 256) {
        const int m0 = g_plan.perm[2 * i], m1 = g_plan.perm[2 * i + 1];
        const float f0 = (m0 >= 0) ? Wr[m0] : 0.f;
        const float f1 = (m1 >= 0) ? Wr[m1] : 0.f;
        Wb[(size_t)r * (NK / 2) + i] = bfpack2(f0, f1);
    }
}

// ---------------------------------------------------------------------------
// Fused, symmetric waves: every wave expands ONE 8-col granule per chunk AND
// runs MFMA on its own 32-col N-band. BM=64, BN=256, BK=64, grid 256, 512 thr.
// 8-slot k-major As ring, barrier per 4-chunk interval, B reg-dbuf from L2.
// ---------------------------------------------------------------------------
#define T_BYTES   (64 * TROW * 4)                 // 39680
#define AS_BYTES  (8 * 8 * 64 * 8 * 2)            // 65536
#define LDS_BYTES (T_BYTES + AS_BYTES)            // 105216

__global__ __launch_bounds__(512, 2) void fused_kernel(
    const float* __restrict__ x,
    const unsigned short* __restrict__ Wb,
    const float* __restrict__ bias,
    float* __restrict__ C)
{
    extern __shared__ char smem[];
    float* T = (float*)smem;
    unsigned short* As = (unsigned short*)(smem + T_BYTES);  // [slot][g][row][8]

    const int t = threadIdx.x, l = t & 63, wid = t >> 6;
    const int lr = l & 15, lk = l >> 4;
    const size_t m0 = (size_t)blockIdx.x * 64;

    // plan registers: each wave owns granule `wid` = quads {2wid, 2wid+1}
    u32x2 ePA[4], ePB[4];
    auto loadPlan = [&](int iv, u32x2 (&e)[4]) {
#pragma unroll
        for (int cc = 0; cc < 4; ++cc)
            e[cc] = *(const u32x2*)(g_plan.cplan + (iv * 4 + cc) * 16 + 2 * wid);
    };
    // B fragments: wave's 32-col band, direct from L2-resident Wb, reg dbuf
    const unsigned short* wbase = Wb + (size_t)(wid * 32 + lr) * NK + lk * 8;
    bf16x8 bA[2][2], bB[2][2];
    auto prefB = [&](int c, bf16x8 (&bf)[2][2]) {
#pragma unroll
        for (int ni = 0; ni < 2; ++ni)
#pragma unroll
            for (int ks = 0; ks < 2; ++ks)
                bf[ni][ks] = *(const bf16x8*)(wbase + (size_t)ni * 16 * NK
                                              + (size_t)c * 64 + ks * 32);
    };
    loadPlan(0, ePA);
    prefB(0, bA);

    // --- prologue: deg1 tanh at permuted positions ------------------------
#pragma unroll
    for (int i = 0; i < 2; ++i) {
        const int v = t * 2 + i;                  // 0..1023
        const int r = v >> 4, f = v & 15;
        const int pf = 17 * f - f * (f - 1) / 2;  // pos_x(f)
        T[r * TROW + pf] = tanhf(x[(m0 + r) * NF + f]);
    }
    if (t < 64) { T[t*TROW + 152] = 1.f; T[t*TROW + 153] = 0.f; T[t*TROW + 154] = 0.f; }
    __syncthreads();
    // --- deg2 -------------------------------------------------------------
    {
        const int r = t >> 3, s = t & 7, base = r * TROW;
#pragma unroll
        for (int i = 0; i < 17; ++i) {
            const unsigned e = g_plan.d2t[s + 8 * i];
            T[base + (e >> 20)] = T[base + (e & 1023u)] * T[base + ((e >> 10) & 1023u)];
        }
    }
    __syncthreads();

    // --- expand: lane = row; one granule (8 cols = 2 quads) per chunk -----
    const int pb = l * TROW;
    auto expand = [&](int c, const u32x2& e2) {
        float v[8];
#pragma unroll
        for (int q = 0; q < 2; ++q) {
            const unsigned eq = e2[q];
            const float lv = T[pb + (eq & 0xffffu)];
            const int   r0 = pb + (int)(eq >> 16);
#pragma unroll
            for (int u = 0; u < 4; ++u) v[q * 4 + u] = lv * T[r0 + u];
        }
        uint4v o;
        o[0] = bfpack2(v[0], v[1]); o[1] = bfpack2(v[2], v[3]);
        o[2] = bfpack2(v[4], v[5]); o[3] = bfpack2(v[6], v[7]);
        const int slot = c & 7;
        *(uint4v*)&As[(((slot * 8 + wid) * 64) + l) * 8] = o;
    };

    f32x4 acc[4][2];
#pragma unroll
    for (int i = 0; i < 4; ++i)
#pragma unroll
        for (int j = 0; j < 2; ++j) acc[i][j] = (f32x4){0.f, 0.f, 0.f, 0.f};

    auto mfmaChunk = [&](int c, bf16x8 (&bf)[2][2]) {
        const int slot = c & 7;
        bf16x8 af[4][2];
#pragma unroll
        for (int mi = 0; mi < 4; ++mi)
#pragma unroll
            for (int ks = 0; ks < 2; ++ks)
                af[mi][ks] = *(const bf16x8*)
                    &As[(((slot * 8 + ks * 4 + lk) * 64) + mi * 16 + lr) * 8];
#pragma unroll
        for (int ks = 0; ks < 2; ++ks)
#pragma unroll
            for (int mi = 0; mi < 4; ++mi)
#pragma unroll
                for (int ni = 0; ni < 2; ++ni)
                    acc[mi][ni] = __builtin_amdgcn_mfma_f32_16x16x32_bf16(
                        af[mi][ks], bf[ni][ks], acc[mi][ni], 0, 0, 0);
    };

    auto body = [&](int iv, u32x2 (&eUse)[4], u32x2 (&eLoad)[4]) {
#pragma unroll
        for (int cc = 0; cc < 4; ++cc) {
            const int c  = iv * 4 + cc;
            const int nc = (c + 1 < NCHUNK) ? c + 1 : c;
            if (cc & 1) { prefB(nc, bA); mfmaChunk(c, bB); }
            else        { prefB(nc, bB); mfmaChunk(c, bA); }
            if (iv + 1 < NIV) expand((iv + 1) * 4 + cc, eUse[cc]);
        }
        if (iv + 2 < NIV) loadPlan(iv + 2, eLoad);
    };

    // pre-loop: expand interval 0 (slots 0-3), plan for interval 1
#pragma unroll
    for (int cc = 0; cc < 4; ++cc) expand(cc, ePA[cc]);
    loadPlan(1, ePB);
    __syncthreads();

    for (int i2 = 0; i2 < NIV; i2 += 2) {
        body(i2, ePB, ePA);
        __syncthreads();
        body(i2 + 1, ePA, ePB);
        __syncthreads();
    }

    // --- epilogue: bias + relu (all waves) --------------------------------
#pragma unroll
    for (int ni = 0; ni < 2; ++ni) {
        const int col = wid * 32 + ni * 16 + lr;
        const float bv = bias[col];
#pragma unroll
        for (int mi = 0; mi < 4; ++mi) {
            const size_t r0 = m0 + mi * 16 + lk * 4;
#pragma unroll
            for (int j = 0; j < 4; ++j)
                C[(r0 + j) * OUTD + col] = fmaxf(acc[mi][ni][j] + bv, 0.f);
        }
    }
}

// ---------------------------------------------------------------------------
// Launch
// ---------------------------------------------------------------------------
extern "C" void kernel_launch(void* const* d_in, const int* in_sizes, int n_in,
                              void* d_out, int out_size, void* d_ws, size_t ws_size,
                              hipStream_t stream)
{
    const float* x    = (const float*)d_in[0];
    const float* W    = (const float*)d_in[1];
    const float* bias = (const float*)d_in[2];
    float* out        = (float*)d_out;

    unsigned* Wb = (unsigned*)d_ws;              // 2.62 MB bf16 permuted W
    (void)hipFuncSetAttribute((const void*)fused_kernel,
                              hipFuncAttributeMaxDynamicSharedMemorySize, LDS_BYTES);
    wconv_kernel<<<OUTD, 256, 0, stream>>>(W, Wb);
    fused_kernel<<<BATCH / 64, 512, LDS_BYTES, stream>>>(
        x, (const unsigned short*)Wb, bias, out);
}